// Round 14
// baseline (206.093 us; speedup 1.0000x reference)
//
#include <hip/hip_runtime.h>
#include <hip/hip_bf16.h>
#include <hip/hip_fp16.h>
#include <cstdint>

#define NN 50000
#define NE 800000
#define NG 64
#define NPB 128                      // nodes per bucket
#define NB ((NN + NPB - 1) / NPB)    // 391 buckets
#define BSTRIDE 4096                 // fixed entries per bucket (mean 2046, 22 sigma)
#define BCAP BSTRIDE
#define ACH 2048                     // edges per bucketA block
#define AEPT 8                       // edges per thread (ACH/256)
#define NKEY (NPB * 8)               // counting-sort keys
#define LOG2E 1.44269504f
#define EDGE_BLOCKS 2048             // persistent edge kernel (8192 waves = full residency)

typedef _Float16 h2 __attribute__((ext_vector_type(2)));

#if defined(__has_builtin)
#if __has_builtin(__builtin_amdgcn_fdot2)
#define HAS_FDOT2 1
#endif
#endif

__device__ __forceinline__ float dot2f(h2 a, h2 b, float c) {
#ifdef HAS_FDOT2
    return __builtin_amdgcn_fdot2(a, b, c, false);
#else
    return c + (float)a[0] * (float)b[0] + (float)a[1] * (float)b[1];
#endif
}

__device__ __forceinline__ h2 bch2(uint32_t u) { return __builtin_bit_cast(h2, u); }

// sum over 8-lane group: quad_perm xor1, xor2, then row_half_mirror (0x141)
__device__ __forceinline__ float row8_sum(float v) {
    int x;
    x = __builtin_amdgcn_update_dpp(0, __builtin_bit_cast(int, v), 0xB1, 0xF, 0xF, true);
    v += __builtin_bit_cast(float, x);
    x = __builtin_amdgcn_update_dpp(0, __builtin_bit_cast(int, v), 0x4E, 0xF, 0xF, true);
    v += __builtin_bit_cast(float, x);
    x = __builtin_amdgcn_update_dpp(0, __builtin_bit_cast(int, v), 0x141, 0xF, 0xF, true);
    v += __builtin_bit_cast(float, x);
    return v;
}

// add value from lane i+8 within the 16-lane row (row_ror:8)
__device__ __forceinline__ float xor8_add(float v) {
    int x = __builtin_amdgcn_update_dpp(0, __builtin_bit_cast(int, v), 0x128, 0xF, 0xF, true);
    return v + __builtin_bit_cast(float, x);
}

// ---------------- init: zero bucket cursors + gsums (replaces memsets) ------

__global__ __launch_bounds__(512) void k_init(int* __restrict__ bcur,
                                              float* __restrict__ gsums) {
    int t = threadIdx.x;
    for (int i = t; i < NB * 16; i += 512) bcur[i] = 0;
    for (int i = t; i < NG * 64; i += 512) gsums[i] = 0.f;
}

// ---------------- bucketA body (block-aggregated scatter, fixed-stride) -----

__device__ __forceinline__ void bucketA_body(
    int bid, const int* __restrict__ ei, const float* __restrict__ euclid,
    int* __restrict__ bcur, uint2* __restrict__ bdata, int E) {
    __shared__ int cnt[NB];
    __shared__ int gb[NB];
    int t = threadIdx.x;
    int base = bid * ACH;
    for (int i = t; i < NB; i += 256) cnt[i] = 0;
    __syncthreads();
    uint2 ent[AEPT];
    int bk[AEPT];
    #pragma unroll
    for (int i = 0; i < AEPT; i++) {
        int e = base + i * 256 + t;
        if (e < E) {
            int s = ei[e];
            int d = ei[NE + e];
            unsigned short wh = __half_as_ushort(__float2half(euclid[e]));
            ent[i] = make_uint2(((uint32_t)wh << 16) | (uint32_t)s, (uint32_t)d);
            bk[i] = d >> 7;
            atomicAdd(&cnt[bk[i]], 1);
        } else {
            bk[i] = -1;
        }
    }
    __syncthreads();
    for (int b = t; b < NB; b += 256) {
        int c = cnt[b];
        int old = c ? atomicAdd(&bcur[b * 16], c) : 0;
        gb[b] = b * BSTRIDE + min(old, BSTRIDE);
        cnt[b] = 0;
    }
    __syncthreads();
    #pragma unroll
    for (int i = 0; i < AEPT; i++) {
        if (bk[i] >= 0) {
            int r = atomicAdd(&cnt[bk[i]], 1);
            int pos = gb[bk[i]] + r;
            if (pos < (bk[i] + 1) * BSTRIDE) bdata[pos] = ent[i];
        }
    }
}

// ---------------- GEMM body (fp16 dot2 dual GEMM) ---------------------------

template <int DIN, typename XT>
__device__ __forceinline__ void gemm_body(
    int gb, const XT* __restrict__ X,
    const float* __restrict__ Wl, const float* __restrict__ bl,
    const float* __restrict__ Wr, const float* __restrict__ br,
    __half* __restrict__ xlh, __half* __restrict__ xrh, int n) {
    constexpr int BK = 16, BM = 64, XS = BM + 4, KP = BK / 2;
    constexpr int NKT = DIN / BK;
    __shared__ h2 sX[2][KP][XS];
    __shared__ h2 sW[2][KP][128];
    int t = threadIdx.x;
    int rb = gb * BM;

    int xrow = t >> 2, xk4 = (t & 3) << 2;
    int wkp = t >> 5, wcol = (t & 31) << 2;
    int rg = min(rb + xrow, n - 1);
    const XT* xp = X + (size_t)rg * DIN + xk4;
    const float* wsrc = (wcol < 64) ? (Wl + (2 * wkp) * 64 + wcol)
                                    : (Wr + (2 * wkp) * 64 + wcol - 64);

    h2 gxa, gxb;
    auto loadX2 = [&](const XT* p, h2& a, h2& bq) {
        if constexpr (sizeof(XT) == 4) {
            float4 f = *(const float4*)p;
            a = h2{(_Float16)f.x, (_Float16)f.y};
            bq = h2{(_Float16)f.z, (_Float16)f.w};
        } else {
            uint2 u = *(const uint2*)p;
            a = bch2(u.x);
            bq = bch2(u.y);
        }
    };
    loadX2(xp, gxa, gxb);
    float4 gwa = *(const float4*)wsrc;
    float4 gwb = *(const float4*)(wsrc + 64);

    auto writeTile = [&](int bu) {
        int kp0 = xk4 >> 1;
        sX[bu][kp0][xrow] = gxa;
        sX[bu][kp0 + 1][xrow] = gxb;
        sW[bu][wkp][wcol]     = h2{(_Float16)gwa.x, (_Float16)gwb.x};
        sW[bu][wkp][wcol + 1] = h2{(_Float16)gwa.y, (_Float16)gwb.y};
        sW[bu][wkp][wcol + 2] = h2{(_Float16)gwa.z, (_Float16)gwb.z};
        sW[bu][wkp][wcol + 3] = h2{(_Float16)gwa.w, (_Float16)gwb.w};
    };
    writeTile(0);
    __syncthreads();

    int tx = t & 15, ty = t >> 4;
    int r0 = ty * 4;
    int c0 = tx * 4;
    float acc[4][8];
    #pragma unroll
    for (int i = 0; i < 4; i++)
        #pragma unroll
        for (int j = 0; j < 8; j++) acc[i][j] = 0.f;

    for (int kt = 0; kt < NKT; ++kt) {
        int cur = kt & 1;
        if (kt + 1 < NKT) {
            loadX2(xp + (kt + 1) * BK, gxa, gxb);
            gwa = *(const float4*)(wsrc + (size_t)(kt + 1) * BK * 64);
            gwb = *(const float4*)(wsrc + (size_t)(kt + 1) * BK * 64 + 64);
        }
        #pragma unroll
        for (int kp = 0; kp < KP; kp++) {
            uint4 xa = *(const uint4*)&sX[cur][kp][r0];
            uint4 wa = *(const uint4*)&sW[cur][kp][c0];
            uint4 wb = *(const uint4*)&sW[cur][kp][64 + c0];
            h2 xv[4] = {bch2(xa.x), bch2(xa.y), bch2(xa.z), bch2(xa.w)};
            h2 wv[8] = {bch2(wa.x), bch2(wa.y), bch2(wa.z), bch2(wa.w),
                        bch2(wb.x), bch2(wb.y), bch2(wb.z), bch2(wb.w)};
            #pragma unroll
            for (int ri = 0; ri < 4; ri++)
                #pragma unroll
                for (int cj = 0; cj < 8; cj++)
                    acc[ri][cj] = dot2f(xv[ri], wv[cj], acc[ri][cj]);
        }
        if (kt + 1 < NKT) writeTile((kt + 1) & 1);
        __syncthreads();
    }

    float4 bl4 = *(const float4*)(bl + c0);
    float4 br4 = *(const float4*)(br + c0);
    #pragma unroll
    for (int ri = 0; ri < 4; ri++) {
        int row = rb + r0 + ri;
        if (row < n) {
            __half2 la = __floats2half2_rn(acc[ri][0] + bl4.x, acc[ri][1] + bl4.y);
            __half2 lb = __floats2half2_rn(acc[ri][2] + bl4.z, acc[ri][3] + bl4.w);
            uint2 ul;
            ul.x = *reinterpret_cast<uint32_t*>(&la);
            ul.y = *reinterpret_cast<uint32_t*>(&lb);
            *(uint2*)(xlh + (size_t)row * 64 + c0) = ul;
            __half2 ra = __floats2half2_rn(acc[ri][4] + br4.x, acc[ri][5] + br4.y);
            __half2 rbq = __floats2half2_rn(acc[ri][6] + br4.z, acc[ri][7] + br4.w);
            uint2 ur;
            ur.x = *reinterpret_cast<uint32_t*>(&ra);
            ur.y = *reinterpret_cast<uint32_t*>(&rbq);
            *(uint2*)(xrh + (size_t)row * 64 + c0) = ur;
        }
    }
}

template <int DIN, typename XT>
__global__ __launch_bounds__(256) void k_gemm4(
    const XT* __restrict__ X,
    const float* __restrict__ Wl, const float* __restrict__ bl,
    const float* __restrict__ Wr, const float* __restrict__ br,
    __half* __restrict__ xlh, __half* __restrict__ xrh, int n) {
    gemm_body<DIN, XT>(blockIdx.x, X, Wl, bl, Wr, br, xlh, xrh, n);
}

// fused phase: bucketA (blocks [0,nA)) || gemm layer 1 (blocks [nA, nA+nG))
__global__ __launch_bounds__(256) void k_phase3(
    const int* __restrict__ ei, const float* __restrict__ euclid,
    int* __restrict__ bcur, uint2* __restrict__ bdata, int E, int nA,
    const float* __restrict__ X,
    const float* __restrict__ Wl, const float* __restrict__ bl,
    const float* __restrict__ Wr, const float* __restrict__ br,
    __half* __restrict__ xlh, __half* __restrict__ xrh, int n) {
    if ((int)blockIdx.x < nA) {
        bucketA_body(blockIdx.x, ei, euclid, bcur, bdata, E);
    } else {
        gemm_body<128, float>(blockIdx.x - nA, X, Wl, bl, Wr, br, xlh, xrh, n);
    }
}

// Phase B: per bucket counting-sort by key=(node_local<<3)|(src>>13);
// writes per-node [start,end) into offs/offsE (bucket segments are strided).
__global__ __launch_bounds__(256) void k_bucketB(
    const int* __restrict__ bcur, const uint2* __restrict__ bdata,
    uint32_t* __restrict__ csr, int* __restrict__ offs,
    int* __restrict__ offsE, int n) {
    __shared__ int cnt[NKEY];
    __shared__ int wsum[4];
    __shared__ int nstart[NPB + 1];
    __shared__ uint2 ent_lds[BCAP];
    __shared__ uint32_t obuf[BCAP];
    int b = blockIdx.x;
    int base_node = b * NPB;
    int nnodes = min(NPB, n - base_node);
    int seg0 = b * BSTRIDE;
    int len = min(bcur[b * 16], BSTRIDE);
    int t = threadIdx.x;
    cnt[t] = 0; cnt[t + 256] = 0; cnt[t + 512] = 0; cnt[t + 768] = 0;
    __syncthreads();
    auto keyof = [&](uint2 e) {
        return ((((int)e.y - base_node) << 3) | (int)((e.x & 0xFFFFu) >> 13));
    };
    for (int i = t; i < len; i += 256) {
        uint2 e = bdata[seg0 + i];
        ent_lds[i] = e;
        atomicAdd(&cnt[keyof(e)], 1);
    }
    __syncthreads();
    int c0 = cnt[4 * t], c1 = cnt[4 * t + 1], c2 = cnt[4 * t + 2], c3 = cnt[4 * t + 3];
    int v = c0 + c1 + c2 + c3;
    int lane = t & 63, wv = t >> 6;
    int s = v;
    #pragma unroll
    for (int off = 1; off < 64; off <<= 1) {
        int u = __shfl_up(s, off);
        if (lane >= off) s += u;
    }
    if (lane == 63) wsum[wv] = s;
    __syncthreads();
    int add = 0;
    for (int w = 0; w < wv; w++) add += wsum[w];
    int e0 = s + add - v;
    int e1 = e0 + c0, e2 = e1 + c1, e3 = e2 + c2;
    __syncthreads();
    cnt[4 * t] = e0; cnt[4 * t + 1] = e1; cnt[4 * t + 2] = e2; cnt[4 * t + 3] = e3;
    if ((t & 1) == 0 && (t >> 1) < NPB) nstart[t >> 1] = e0;
    if (t == 0) nstart[nnodes] = len;
    __syncthreads();
    if (t < nnodes) {
        offs[base_node + t]  = seg0 + nstart[t];
        offsE[base_node + t] = seg0 + ((t + 1 < nnodes) ? nstart[t + 1] : len);
    }
    for (int i = t; i < len; i += 256) {
        uint2 e = ent_lds[i];
        int pos = atomicAdd(&cnt[keyof(e)], 1);
        obuf[pos] = e.x;
    }
    __syncthreads();
    for (int i = t; i < len; i += 256) csr[seg0 + i] = obuf[i];
}

// ---------------- edge kernel: persistent waves, 8 edges x 8 lanes ----------
// Layer constants (We/att/cb) loaded ONCE per wave; grid-stride over nodes.

__global__ __launch_bounds__(256) void k_edge(
    const __half* __restrict__ xlh, const __half* __restrict__ xrh,
    const int* __restrict__ offs, const int* __restrict__ offsE,
    const uint32_t* __restrict__ csr,
    const float* __restrict__ We, const float* __restrict__ att,
    const float* __restrict__ cb, __half* __restrict__ hout, int n) {
    int lane = threadIdx.x & 63;
    int fg = lane & 7;
    int eg = lane >> 3;
    int wid = (blockIdx.x * blockDim.x + threadIdx.x) >> 6;
    int nw = (gridDim.x * blockDim.x) >> 6;

    // layer-constant preamble (once per wave)
    float4 cba = *(const float4*)(cb + fg * 8);
    float4 cbb = *(const float4*)(cb + fg * 8 + 4);
    float4 Wea = *(const float4*)(We + fg * 8);
    float4 Web = *(const float4*)(We + fg * 8 + 4);
    float4 ata = *(const float4*)(att + fg * 8);
    float4 atb = *(const float4*)(att + fg * 8 + 4);
    h2 We0 = {(_Float16)Wea.x, (_Float16)Wea.y};
    h2 We1 = {(_Float16)Wea.z, (_Float16)Wea.w};
    h2 We2 = {(_Float16)Web.x, (_Float16)Web.y};
    h2 We3 = {(_Float16)Web.z, (_Float16)Web.w};
    h2 at0 = {(_Float16)(ata.x * LOG2E), (_Float16)(ata.y * LOG2E)};
    h2 at1 = {(_Float16)(ata.z * LOG2E), (_Float16)(ata.w * LOG2E)};
    h2 at2 = {(_Float16)(atb.x * LOG2E), (_Float16)(atb.y * LOG2E)};
    h2 at3 = {(_Float16)(atb.z * LOG2E), (_Float16)(atb.w * LOG2E)};
    const h2 k02 = {(_Float16)0.2f, (_Float16)0.2f};
    const char* xbase = (const char*)xlh;
    uint32_t foff = (uint32_t)fg << 4;

    for (int d = wid; d < n; d += nw) {
        int s0 = offs[d], s1 = offsE[d];
        int deg = s1 - s0;

        if (deg <= 0) {
            if (eg == 0) {
                __half2 a = __floats2half2_rn(fmaxf(cba.x, 0.f), fmaxf(cba.y, 0.f));
                __half2 b = __floats2half2_rn(fmaxf(cba.z, 0.f), fmaxf(cba.w, 0.f));
                __half2 c = __floats2half2_rn(fmaxf(cbb.x, 0.f), fmaxf(cbb.y, 0.f));
                __half2 e = __floats2half2_rn(fmaxf(cbb.z, 0.f), fmaxf(cbb.w, 0.f));
                uint4 uo;
                uo.x = *reinterpret_cast<uint32_t*>(&a);
                uo.y = *reinterpret_cast<uint32_t*>(&b);
                uo.z = *reinterpret_cast<uint32_t*>(&c);
                uo.w = *reinterpret_cast<uint32_t*>(&e);
                *(uint4*)(hout + (size_t)d * 64 + fg * 8) = uo;
            }
            continue;
        }

        uint4 xru = *(const uint4*)(xrh + (size_t)d * 64 + fg * 8);
        h2 xr0 = bch2(xru.x), xr1 = bch2(xru.y), xr2 = bch2(xru.z), xr3 = bch2(xru.w);

        float a0 = 0.f, a1 = 0.f, a2 = 0.f, a3 = 0.f;
        float a4 = 0.f, a5 = 0.f, a6 = 0.f, a7 = 0.f, sum = 0.f;

        int idx0 = min(eg, deg - 1);
        uint32_t ent = csr[s0 + idx0];
        uint4 raw = *(const uint4*)(xbase + ((ent & 0xFFFFu) << 7) + foff);

        for (int base = 0; base < deg; base += 8) {
            bool valid = (base + eg) < deg;
            uint32_t ent_n = ent;
            uint4 raw_n = raw;
            if (base + 8 < deg) {
                int idx2 = min(base + 8 + eg, deg - 1);
                ent_n = csr[s0 + idx2];
                raw_n = *(const uint4*)(xbase + ((ent_n & 0xFFFFu) << 7) + foff);
            }
            h2 xl0 = bch2(raw.x), xl1 = bch2(raw.y), xl2 = bch2(raw.z), xl3 = bch2(raw.w);
            _Float16 wh = __builtin_bit_cast(_Float16, (unsigned short)(ent >> 16));
            h2 w2 = {wh, wh};
            h2 m0 = xl0 + (w2 * We0 + xr0);
            h2 m1 = xl1 + (w2 * We1 + xr1);
            h2 m2 = xl2 + (w2 * We2 + xr2);
            h2 m3 = xl3 + (w2 * We3 + xr3);
            h2 l0 = __builtin_elementwise_max(m0, m0 * k02);
            h2 l1 = __builtin_elementwise_max(m1, m1 * k02);
            h2 l2 = __builtin_elementwise_max(m2, m2 * k02);
            h2 l3 = __builtin_elementwise_max(m3, m3 * k02);
            float p = dot2f(l3, at3, dot2f(l2, at2, dot2f(l1, at1, dot2f(l0, at0, 0.f))));
            p = row8_sum(p);
            float wp = valid ? exp2f(p) : 0.f;
            a0 = fmaf(wp, (float)xl0[0], a0);
            a1 = fmaf(wp, (float)xl0[1], a1);
            a2 = fmaf(wp, (float)xl1[0], a2);
            a3 = fmaf(wp, (float)xl1[1], a3);
            a4 = fmaf(wp, (float)xl2[0], a4);
            a5 = fmaf(wp, (float)xl2[1], a5);
            a6 = fmaf(wp, (float)xl3[0], a6);
            a7 = fmaf(wp, (float)xl3[1], a7);
            sum += wp;
            ent = ent_n;
            raw = raw_n;
        }

        sum = xor8_add(sum);
        a0 = xor8_add(a0); a1 = xor8_add(a1); a2 = xor8_add(a2); a3 = xor8_add(a3);
        a4 = xor8_add(a4); a5 = xor8_add(a5); a6 = xor8_add(a6); a7 = xor8_add(a7);
        #pragma unroll
        for (int off = 16; off <= 32; off <<= 1) {
            sum += __shfl_xor(sum, off);
            a0 += __shfl_xor(a0, off); a1 += __shfl_xor(a1, off);
            a2 += __shfl_xor(a2, off); a3 += __shfl_xor(a3, off);
            a4 += __shfl_xor(a4, off); a5 += __shfl_xor(a5, off);
            a6 += __shfl_xor(a6, off); a7 += __shfl_xor(a7, off);
        }

        if (eg == 0) {
            float inv = 1.0f / sum;
            __half2 a = __floats2half2_rn(fmaxf(a0 * inv + cba.x, 0.f),
                                          fmaxf(a1 * inv + cba.y, 0.f));
            __half2 b = __floats2half2_rn(fmaxf(a2 * inv + cba.z, 0.f),
                                          fmaxf(a3 * inv + cba.w, 0.f));
            __half2 c = __floats2half2_rn(fmaxf(a4 * inv + cbb.x, 0.f),
                                          fmaxf(a5 * inv + cbb.y, 0.f));
            __half2 e = __floats2half2_rn(fmaxf(a6 * inv + cbb.z, 0.f),
                                          fmaxf(a7 * inv + cbb.w, 0.f));
            uint4 uo;
            uo.x = *reinterpret_cast<uint32_t*>(&a);
            uo.y = *reinterpret_cast<uint32_t*>(&b);
            uo.z = *reinterpret_cast<uint32_t*>(&c);
            uo.w = *reinterpret_cast<uint32_t*>(&e);
            *(uint4*)(hout + (size_t)d * 64 + fg * 8) = uo;
        }
    }
}

// ---------------- fused pooling + head: one block per graph -----------------

__global__ __launch_bounds__(512) void k_pool(
    const __half* __restrict__ h, const int* __restrict__ batch,
    const float* __restrict__ Wlin, const float* __restrict__ blin,
    float* __restrict__ out, int n) {
    __shared__ float red[8][64];
    int g = blockIdx.x;
    int t = threadIdx.x, lane = t & 63, wv = t >> 6;
    int lo = 0, hi = n;
    while (lo < hi) { int mid = (lo + hi) >> 1; if (batch[mid] < g) lo = mid + 1; else hi = mid; }
    int start = lo;
    lo = start; hi = n;
    while (lo < hi) { int mid = (lo + hi) >> 1; if (batch[mid] < g + 1) lo = mid + 1; else hi = mid; }
    int end = lo, cnt = end - start;
    float acc = 0.f;
    for (int r = start + wv; r < end; r += 8)
        acc += __half2float(h[(size_t)r * 64 + lane]);
    red[wv][lane] = acc;
    __syncthreads();
    if (wv == 0) {
        float s = red[0][lane];
        #pragma unroll
        for (int w = 1; w < 8; w++) s += red[w][lane];
        float pooled = s / (float)(cnt > 0 ? cnt : 1);
        float p0 = pooled * Wlin[lane * 2 + 0];
        float p1 = pooled * Wlin[lane * 2 + 1];
        #pragma unroll
        for (int off = 32; off > 0; off >>= 1) {
            p0 += __shfl_xor(p0, off);
            p1 += __shfl_xor(p1, off);
        }
        if (lane == 0) {
            p0 += blin[0]; p1 += blin[1];
            float m = fmaxf(p0, p1);
            float e0 = __expf(p0 - m), e1 = __expf(p1 - m);
            float ss = e0 + e1;
            out[g * 2 + 0] = e0 / ss;
            out[g * 2 + 1] = e1 / ss;
        }
    }
}

// ---------------- launch ----------------

extern "C" void kernel_launch(void* const* d_in, const int* in_sizes, int n_in,
                              void* d_out, int out_size, void* d_ws, size_t ws_size,
                              hipStream_t stream) {
    const float* x      = (const float*)d_in[0];
    const int*   ei     = (const int*)d_in[1];
    const float* euclid = (const float*)d_in[2];
    const int*   batch  = (const int*)d_in[3];
    auto P = [&](int i) { return (const float*)d_in[i]; };

    uintptr_t base = (uintptr_t)d_ws;
    auto carve = [&](size_t bytes) {
        uintptr_t r = base;
        base += (bytes + 255) & ~(size_t)255;
        return (void*)r;
    };
    __half* xlh    = (__half*)carve((size_t)NN * 64 * 2);
    __half* xrh    = (__half*)carve((size_t)NN * 64 * 2);
    __half* h1     = (__half*)carve((size_t)NN * 64 * 2);
    __half* h2b    = (__half*)carve((size_t)NN * 64 * 2);
    int*   offs    = (int*)carve((size_t)NN * 4);
    int*   offsE   = (int*)carve((size_t)NN * 4);
    int*   bcur    = (int*)carve((size_t)NB * 16 * 4);
    uint2* bdata   = (uint2*)carve((size_t)NB * BSTRIDE * 8);
    uint32_t* csr  = (uint32_t*)carve((size_t)NB * BSTRIDE * 4);
    float* gsums   = (float*)carve((size_t)NG * 64 * 4);

    int nA = (NE + ACH - 1) / ACH;            // 391 bucketA blocks
    int nGemmBlocks = (NN + 63) / 64;         // 782 gemm blocks

    k_init<<<1, 512, 0, stream>>>(bcur, gsums);
    // fused: bucketA || gemm layer 1 (independent work)
    k_phase3<<<nA + nGemmBlocks, 256, 0, stream>>>(
        ei, euclid, bcur, bdata, NE, nA,
        x, P(4), P(5), P(6), P(7), xlh, xrh, NN);
    k_bucketB<<<NB, 256, 0, stream>>>(bcur, bdata, csr, offs, offsE, NN);

    k_edge<<<EDGE_BLOCKS, 256, 0, stream>>>(xlh, xrh, offs, offsE, csr, P(8), P(9), P(10), h1, NN);
    // layer 2: h1 fp16
    k_gemm4<64, __half><<<nGemmBlocks, 256, 0, stream>>>(h1, P(11), P(12), P(13), P(14), xlh, xrh, NN);
    k_edge<<<EDGE_BLOCKS, 256, 0, stream>>>(xlh, xrh, offs, offsE, csr, P(15), P(16), P(17), h2b, NN);
    // layer 3: h2 fp16
    k_gemm4<64, __half><<<nGemmBlocks, 256, 0, stream>>>(h2b, P(18), P(19), P(20), P(21), xlh, xrh, NN);
    k_edge<<<EDGE_BLOCKS, 256, 0, stream>>>(xlh, xrh, offs, offsE, csr, P(22), P(23), P(24), h1, NN);

    k_pool<<<NG, 512, 0, stream>>>(h1, batch, P(25), P(26), (float*)d_out, NN);
}

// Round 15
// 199.573 us; speedup vs baseline: 1.0327x; 1.0327x over previous
//
#include <hip/hip_runtime.h>
#include <hip/hip_bf16.h>
#include <hip/hip_fp16.h>
#include <cstdint>

#define NN 50000
#define NE 800000
#define NG 64
#define NPB 128                      // nodes per bucket
#define NB ((NN + NPB - 1) / NPB)    // 391 buckets
#define BSTRIDE 4096                 // fixed entries per bucket (mean 2046, 22 sigma)
#define BCAP BSTRIDE
#define ACH 4096                     // edges per bucketA block
#define AEPT 16                      // edges per thread (ACH/256)
#define NKEY (NPB * 8)               // counting-sort keys
#define LOG2E 1.44269504f

typedef _Float16 h2 __attribute__((ext_vector_type(2)));

#if defined(__has_builtin)
#if __has_builtin(__builtin_amdgcn_fdot2)
#define HAS_FDOT2 1
#endif
#endif

__device__ __forceinline__ float dot2f(h2 a, h2 b, float c) {
#ifdef HAS_FDOT2
    return __builtin_amdgcn_fdot2(a, b, c, false);
#else
    return c + (float)a[0] * (float)b[0] + (float)a[1] * (float)b[1];
#endif
}

__device__ __forceinline__ h2 bch2(uint32_t u) { return __builtin_bit_cast(h2, u); }

// sum over 8-lane group: quad_perm xor1, xor2, then row_half_mirror (0x141)
__device__ __forceinline__ float row8_sum(float v) {
    int x;
    x = __builtin_amdgcn_update_dpp(0, __builtin_bit_cast(int, v), 0xB1, 0xF, 0xF, true);
    v += __builtin_bit_cast(float, x);
    x = __builtin_amdgcn_update_dpp(0, __builtin_bit_cast(int, v), 0x4E, 0xF, 0xF, true);
    v += __builtin_bit_cast(float, x);
    x = __builtin_amdgcn_update_dpp(0, __builtin_bit_cast(int, v), 0x141, 0xF, 0xF, true);
    v += __builtin_bit_cast(float, x);
    return v;
}

// add value from lane i+8 within the 16-lane row (row_ror:8)
__device__ __forceinline__ float xor8_add(float v) {
    int x = __builtin_amdgcn_update_dpp(0, __builtin_bit_cast(int, v), 0x128, 0xF, 0xF, true);
    return v + __builtin_bit_cast(float, x);
}

// ---------------- init: zero bucket cursors (replaces memsets) --------------

__global__ __launch_bounds__(512) void k_init(int* __restrict__ bcur) {
    int t = threadIdx.x;
    for (int i = t; i < NB * 16; i += 512) bcur[i] = 0;
}

// ---------------- bucketA body (block-aggregated scatter, fixed-stride) -----

__device__ __forceinline__ void bucketA_body(
    int bid, const int* __restrict__ ei, const float* __restrict__ euclid,
    int* __restrict__ bcur, uint2* __restrict__ bdata, int E) {
    __shared__ int cnt[NB];
    __shared__ int gb[NB];
    int t = threadIdx.x;
    int base = bid * ACH;
    for (int i = t; i < NB; i += 256) cnt[i] = 0;
    __syncthreads();
    uint2 ent[AEPT];
    int bk[AEPT];
    #pragma unroll
    for (int i = 0; i < AEPT; i++) {
        int e = base + i * 256 + t;
        if (e < E) {
            int s = ei[e];
            int d = ei[NE + e];
            unsigned short wh = __half_as_ushort(__float2half(euclid[e]));
            ent[i] = make_uint2(((uint32_t)wh << 16) | (uint32_t)s, (uint32_t)d);
            bk[i] = d >> 7;
            atomicAdd(&cnt[bk[i]], 1);
        } else {
            bk[i] = -1;
        }
    }
    __syncthreads();
    for (int b = t; b < NB; b += 256) {
        int c = cnt[b];
        int old = c ? atomicAdd(&bcur[b * 16], c) : 0;
        gb[b] = b * BSTRIDE + min(old, BSTRIDE);
        cnt[b] = 0;
    }
    __syncthreads();
    #pragma unroll
    for (int i = 0; i < AEPT; i++) {
        if (bk[i] >= 0) {
            int r = atomicAdd(&cnt[bk[i]], 1);
            int pos = gb[bk[i]] + r;
            if (pos < (bk[i] + 1) * BSTRIDE) bdata[pos] = ent[i];
        }
    }
}

// ---------------- GEMM body (fp16 dot2 dual GEMM) ---------------------------

template <int DIN, typename XT>
__device__ __forceinline__ void gemm_body(
    int gb, const XT* __restrict__ X,
    const float* __restrict__ Wl, const float* __restrict__ bl,
    const float* __restrict__ Wr, const float* __restrict__ br,
    __half* __restrict__ xlh, __half* __restrict__ xrh, int n) {
    constexpr int BK = 16, BM = 64, XS = BM + 4, KP = BK / 2;
    constexpr int NKT = DIN / BK;
    __shared__ h2 sX[2][KP][XS];
    __shared__ h2 sW[2][KP][128];
    int t = threadIdx.x;
    int rb = gb * BM;

    int xrow = t >> 2, xk4 = (t & 3) << 2;
    int wkp = t >> 5, wcol = (t & 31) << 2;
    int rg = min(rb + xrow, n - 1);
    const XT* xp = X + (size_t)rg * DIN + xk4;
    const float* wsrc = (wcol < 64) ? (Wl + (2 * wkp) * 64 + wcol)
                                    : (Wr + (2 * wkp) * 64 + wcol - 64);

    h2 gxa, gxb;
    auto loadX2 = [&](const XT* p, h2& a, h2& bq) {
        if constexpr (sizeof(XT) == 4) {
            float4 f = *(const float4*)p;
            a = h2{(_Float16)f.x, (_Float16)f.y};
            bq = h2{(_Float16)f.z, (_Float16)f.w};
        } else {
            uint2 u = *(const uint2*)p;
            a = bch2(u.x);
            bq = bch2(u.y);
        }
    };
    loadX2(xp, gxa, gxb);
    float4 gwa = *(const float4*)wsrc;
    float4 gwb = *(const float4*)(wsrc + 64);

    auto writeTile = [&](int bu) {
        int kp0 = xk4 >> 1;
        sX[bu][kp0][xrow] = gxa;
        sX[bu][kp0 + 1][xrow] = gxb;
        sW[bu][wkp][wcol]     = h2{(_Float16)gwa.x, (_Float16)gwb.x};
        sW[bu][wkp][wcol + 1] = h2{(_Float16)gwa.y, (_Float16)gwb.y};
        sW[bu][wkp][wcol + 2] = h2{(_Float16)gwa.z, (_Float16)gwb.z};
        sW[bu][wkp][wcol + 3] = h2{(_Float16)gwa.w, (_Float16)gwb.w};
    };
    writeTile(0);
    __syncthreads();

    int tx = t & 15, ty = t >> 4;
    int r0 = ty * 4;
    int c0 = tx * 4;
    float acc[4][8];
    #pragma unroll
    for (int i = 0; i < 4; i++)
        #pragma unroll
        for (int j = 0; j < 8; j++) acc[i][j] = 0.f;

    for (int kt = 0; kt < NKT; ++kt) {
        int cur = kt & 1;
        if (kt + 1 < NKT) {
            loadX2(xp + (kt + 1) * BK, gxa, gxb);
            gwa = *(const float4*)(wsrc + (size_t)(kt + 1) * BK * 64);
            gwb = *(const float4*)(wsrc + (size_t)(kt + 1) * BK * 64 + 64);
        }
        #pragma unroll
        for (int kp = 0; kp < KP; kp++) {
            uint4 xa = *(const uint4*)&sX[cur][kp][r0];
            uint4 wa = *(const uint4*)&sW[cur][kp][c0];
            uint4 wb = *(const uint4*)&sW[cur][kp][64 + c0];
            h2 xv[4] = {bch2(xa.x), bch2(xa.y), bch2(xa.z), bch2(xa.w)};
            h2 wv[8] = {bch2(wa.x), bch2(wa.y), bch2(wa.z), bch2(wa.w),
                        bch2(wb.x), bch2(wb.y), bch2(wb.z), bch2(wb.w)};
            #pragma unroll
            for (int ri = 0; ri < 4; ri++)
                #pragma unroll
                for (int cj = 0; cj < 8; cj++)
                    acc[ri][cj] = dot2f(xv[ri], wv[cj], acc[ri][cj]);
        }
        if (kt + 1 < NKT) writeTile((kt + 1) & 1);
        __syncthreads();
    }

    float4 bl4 = *(const float4*)(bl + c0);
    float4 br4 = *(const float4*)(br + c0);
    #pragma unroll
    for (int ri = 0; ri < 4; ri++) {
        int row = rb + r0 + ri;
        if (row < n) {
            __half2 la = __floats2half2_rn(acc[ri][0] + bl4.x, acc[ri][1] + bl4.y);
            __half2 lb = __floats2half2_rn(acc[ri][2] + bl4.z, acc[ri][3] + bl4.w);
            uint2 ul;
            ul.x = *reinterpret_cast<uint32_t*>(&la);
            ul.y = *reinterpret_cast<uint32_t*>(&lb);
            *(uint2*)(xlh + (size_t)row * 64 + c0) = ul;
            __half2 ra = __floats2half2_rn(acc[ri][4] + br4.x, acc[ri][5] + br4.y);
            __half2 rbq = __floats2half2_rn(acc[ri][6] + br4.z, acc[ri][7] + br4.w);
            uint2 ur;
            ur.x = *reinterpret_cast<uint32_t*>(&ra);
            ur.y = *reinterpret_cast<uint32_t*>(&rbq);
            *(uint2*)(xrh + (size_t)row * 64 + c0) = ur;
        }
    }
}

template <int DIN, typename XT>
__global__ __launch_bounds__(256) void k_gemm4(
    const XT* __restrict__ X,
    const float* __restrict__ Wl, const float* __restrict__ bl,
    const float* __restrict__ Wr, const float* __restrict__ br,
    __half* __restrict__ xlh, __half* __restrict__ xrh, int n) {
    gemm_body<DIN, XT>(blockIdx.x, X, Wl, bl, Wr, br, xlh, xrh, n);
}

// fused phase: bucketA (blocks [0,nA)) || gemm layer 1 (blocks [nA, nA+nG))
__global__ __launch_bounds__(256) void k_phase3(
    const int* __restrict__ ei, const float* __restrict__ euclid,
    int* __restrict__ bcur, uint2* __restrict__ bdata, int E, int nA,
    const float* __restrict__ X,
    const float* __restrict__ Wl, const float* __restrict__ bl,
    const float* __restrict__ Wr, const float* __restrict__ br,
    __half* __restrict__ xlh, __half* __restrict__ xrh, int n) {
    if ((int)blockIdx.x < nA) {
        bucketA_body(blockIdx.x, ei, euclid, bcur, bdata, E);
    } else {
        gemm_body<128, float>(blockIdx.x - nA, X, Wl, bl, Wr, br, xlh, xrh, n);
    }
}

// Phase B: per bucket counting-sort by key=(node_local<<3)|(src>>13);
// writes per-node [start,end) into offs/offsE (bucket segments are strided).
__global__ __launch_bounds__(256) void k_bucketB(
    const int* __restrict__ bcur, const uint2* __restrict__ bdata,
    uint32_t* __restrict__ csr, int* __restrict__ offs,
    int* __restrict__ offsE, int n) {
    __shared__ int cnt[NKEY];
    __shared__ int wsum[4];
    __shared__ int nstart[NPB + 1];
    __shared__ uint2 ent_lds[BCAP];
    __shared__ uint32_t obuf[BCAP];
    int b = blockIdx.x;
    int base_node = b * NPB;
    int nnodes = min(NPB, n - base_node);
    int seg0 = b * BSTRIDE;
    int len = min(bcur[b * 16], BSTRIDE);
    int t = threadIdx.x;
    cnt[t] = 0; cnt[t + 256] = 0; cnt[t + 512] = 0; cnt[t + 768] = 0;
    __syncthreads();
    auto keyof = [&](uint2 e) {
        return ((((int)e.y - base_node) << 3) | (int)((e.x & 0xFFFFu) >> 13));
    };
    for (int i = t; i < len; i += 256) {
        uint2 e = bdata[seg0 + i];
        ent_lds[i] = e;
        atomicAdd(&cnt[keyof(e)], 1);
    }
    __syncthreads();
    int c0 = cnt[4 * t], c1 = cnt[4 * t + 1], c2 = cnt[4 * t + 2], c3 = cnt[4 * t + 3];
    int v = c0 + c1 + c2 + c3;
    int lane = t & 63, wv = t >> 6;
    int s = v;
    #pragma unroll
    for (int off = 1; off < 64; off <<= 1) {
        int u = __shfl_up(s, off);
        if (lane >= off) s += u;
    }
    if (lane == 63) wsum[wv] = s;
    __syncthreads();
    int add = 0;
    for (int w = 0; w < wv; w++) add += wsum[w];
    int e0 = s + add - v;
    int e1 = e0 + c0, e2 = e1 + c1, e3 = e2 + c2;
    __syncthreads();
    cnt[4 * t] = e0; cnt[4 * t + 1] = e1; cnt[4 * t + 2] = e2; cnt[4 * t + 3] = e3;
    if ((t & 1) == 0 && (t >> 1) < NPB) nstart[t >> 1] = e0;
    if (t == 0) nstart[nnodes] = len;
    __syncthreads();
    if (t < nnodes) {
        offs[base_node + t]  = seg0 + nstart[t];
        offsE[base_node + t] = seg0 + ((t + 1 < nnodes) ? nstart[t + 1] : len);
    }
    for (int i = t; i < len; i += 256) {
        uint2 e = ent_lds[i];
        int pos = atomicAdd(&cnt[keyof(e)], 1);
        obuf[pos] = e.x;
    }
    __syncthreads();
    for (int i = t; i < len; i += 256) csr[seg0 + i] = obuf[i];
}

// ---------------- edge kernel: wave per 2 contiguous nodes, 8 edges x 8 lanes
// Non-persistent (HW balances blocks); layer constants hoisted per wave.

__global__ __launch_bounds__(256) void k_edge(
    const __half* __restrict__ xlh, const __half* __restrict__ xrh,
    const int* __restrict__ offs, const int* __restrict__ offsE,
    const uint32_t* __restrict__ csr,
    const float* __restrict__ We, const float* __restrict__ att,
    const float* __restrict__ cb, __half* __restrict__ hout, int n) {
    int lane = threadIdx.x & 63;
    int fg = lane & 7;
    int eg = lane >> 3;
    int wid = (blockIdx.x * blockDim.x + threadIdx.x) >> 6;
    int d0 = wid * 2;
    if (d0 >= n) return;
    int dend = min(d0 + 2, n);

    // layer-constant preamble (once per wave, amortized over 2 nodes)
    float4 cba = *(const float4*)(cb + fg * 8);
    float4 cbb = *(const float4*)(cb + fg * 8 + 4);
    float4 Wea = *(const float4*)(We + fg * 8);
    float4 Web = *(const float4*)(We + fg * 8 + 4);
    float4 ata = *(const float4*)(att + fg * 8);
    float4 atb = *(const float4*)(att + fg * 8 + 4);
    h2 We0 = {(_Float16)Wea.x, (_Float16)Wea.y};
    h2 We1 = {(_Float16)Wea.z, (_Float16)Wea.w};
    h2 We2 = {(_Float16)Web.x, (_Float16)Web.y};
    h2 We3 = {(_Float16)Web.z, (_Float16)Web.w};
    h2 at0 = {(_Float16)(ata.x * LOG2E), (_Float16)(ata.y * LOG2E)};
    h2 at1 = {(_Float16)(ata.z * LOG2E), (_Float16)(ata.w * LOG2E)};
    h2 at2 = {(_Float16)(atb.x * LOG2E), (_Float16)(atb.y * LOG2E)};
    h2 at3 = {(_Float16)(atb.z * LOG2E), (_Float16)(atb.w * LOG2E)};
    const h2 k02 = {(_Float16)0.2f, (_Float16)0.2f};
    const char* xbase = (const char*)xlh;
    uint32_t foff = (uint32_t)fg << 4;

    for (int d = d0; d < dend; ++d) {
        int s0 = offs[d], s1 = offsE[d];
        int deg = s1 - s0;

        if (deg <= 0) {
            if (eg == 0) {
                __half2 a = __floats2half2_rn(fmaxf(cba.x, 0.f), fmaxf(cba.y, 0.f));
                __half2 b = __floats2half2_rn(fmaxf(cba.z, 0.f), fmaxf(cba.w, 0.f));
                __half2 c = __floats2half2_rn(fmaxf(cbb.x, 0.f), fmaxf(cbb.y, 0.f));
                __half2 e = __floats2half2_rn(fmaxf(cbb.z, 0.f), fmaxf(cbb.w, 0.f));
                uint4 uo;
                uo.x = *reinterpret_cast<uint32_t*>(&a);
                uo.y = *reinterpret_cast<uint32_t*>(&b);
                uo.z = *reinterpret_cast<uint32_t*>(&c);
                uo.w = *reinterpret_cast<uint32_t*>(&e);
                *(uint4*)(hout + (size_t)d * 64 + fg * 8) = uo;
            }
            continue;
        }

        uint4 xru = *(const uint4*)(xrh + (size_t)d * 64 + fg * 8);
        h2 xr0 = bch2(xru.x), xr1 = bch2(xru.y), xr2 = bch2(xru.z), xr3 = bch2(xru.w);

        float a0 = 0.f, a1 = 0.f, a2 = 0.f, a3 = 0.f;
        float a4 = 0.f, a5 = 0.f, a6 = 0.f, a7 = 0.f, sum = 0.f;

        int idx0 = min(eg, deg - 1);
        uint32_t ent = csr[s0 + idx0];
        uint4 raw = *(const uint4*)(xbase + ((ent & 0xFFFFu) << 7) + foff);

        for (int base = 0; base < deg; base += 8) {
            bool valid = (base + eg) < deg;
            uint32_t ent_n = ent;
            uint4 raw_n = raw;
            if (base + 8 < deg) {
                int idx2 = min(base + 8 + eg, deg - 1);
                ent_n = csr[s0 + idx2];
                raw_n = *(const uint4*)(xbase + ((ent_n & 0xFFFFu) << 7) + foff);
            }
            h2 xl0 = bch2(raw.x), xl1 = bch2(raw.y), xl2 = bch2(raw.z), xl3 = bch2(raw.w);
            _Float16 wh = __builtin_bit_cast(_Float16, (unsigned short)(ent >> 16));
            h2 w2 = {wh, wh};
            h2 m0 = xl0 + (w2 * We0 + xr0);
            h2 m1 = xl1 + (w2 * We1 + xr1);
            h2 m2 = xl2 + (w2 * We2 + xr2);
            h2 m3 = xl3 + (w2 * We3 + xr3);
            h2 l0 = __builtin_elementwise_max(m0, m0 * k02);
            h2 l1 = __builtin_elementwise_max(m1, m1 * k02);
            h2 l2 = __builtin_elementwise_max(m2, m2 * k02);
            h2 l3 = __builtin_elementwise_max(m3, m3 * k02);
            float p = dot2f(l3, at3, dot2f(l2, at2, dot2f(l1, at1, dot2f(l0, at0, 0.f))));
            p = row8_sum(p);
            float wp = valid ? exp2f(p) : 0.f;
            a0 = fmaf(wp, (float)xl0[0], a0);
            a1 = fmaf(wp, (float)xl0[1], a1);
            a2 = fmaf(wp, (float)xl1[0], a2);
            a3 = fmaf(wp, (float)xl1[1], a3);
            a4 = fmaf(wp, (float)xl2[0], a4);
            a5 = fmaf(wp, (float)xl2[1], a5);
            a6 = fmaf(wp, (float)xl3[0], a6);
            a7 = fmaf(wp, (float)xl3[1], a7);
            sum += wp;
            ent = ent_n;
            raw = raw_n;
        }

        sum = xor8_add(sum);
        a0 = xor8_add(a0); a1 = xor8_add(a1); a2 = xor8_add(a2); a3 = xor8_add(a3);
        a4 = xor8_add(a4); a5 = xor8_add(a5); a6 = xor8_add(a6); a7 = xor8_add(a7);
        #pragma unroll
        for (int off = 16; off <= 32; off <<= 1) {
            sum += __shfl_xor(sum, off);
            a0 += __shfl_xor(a0, off); a1 += __shfl_xor(a1, off);
            a2 += __shfl_xor(a2, off); a3 += __shfl_xor(a3, off);
            a4 += __shfl_xor(a4, off); a5 += __shfl_xor(a5, off);
            a6 += __shfl_xor(a6, off); a7 += __shfl_xor(a7, off);
        }

        if (eg == 0) {
            float inv = 1.0f / sum;
            __half2 a = __floats2half2_rn(fmaxf(a0 * inv + cba.x, 0.f),
                                          fmaxf(a1 * inv + cba.y, 0.f));
            __half2 b = __floats2half2_rn(fmaxf(a2 * inv + cba.z, 0.f),
                                          fmaxf(a3 * inv + cba.w, 0.f));
            __half2 c = __floats2half2_rn(fmaxf(a4 * inv + cbb.x, 0.f),
                                          fmaxf(a5 * inv + cbb.y, 0.f));
            __half2 e = __floats2half2_rn(fmaxf(a6 * inv + cbb.z, 0.f),
                                          fmaxf(a7 * inv + cbb.w, 0.f));
            uint4 uo;
            uo.x = *reinterpret_cast<uint32_t*>(&a);
            uo.y = *reinterpret_cast<uint32_t*>(&b);
            uo.z = *reinterpret_cast<uint32_t*>(&c);
            uo.w = *reinterpret_cast<uint32_t*>(&e);
            *(uint4*)(hout + (size_t)d * 64 + fg * 8) = uo;
        }
    }
}

// ---------------- fused pooling + head: one block per graph -----------------

__global__ __launch_bounds__(512) void k_pool(
    const __half* __restrict__ h, const int* __restrict__ batch,
    const float* __restrict__ Wlin, const float* __restrict__ blin,
    float* __restrict__ out, int n) {
    __shared__ float red[8][64];
    int g = blockIdx.x;
    int t = threadIdx.x, lane = t & 63, wv = t >> 6;
    int lo = 0, hi = n;
    while (lo < hi) { int mid = (lo + hi) >> 1; if (batch[mid] < g) lo = mid + 1; else hi = mid; }
    int start = lo;
    lo = start; hi = n;
    while (lo < hi) { int mid = (lo + hi) >> 1; if (batch[mid] < g + 1) lo = mid + 1; else hi = mid; }
    int end = lo, cnt = end - start;
    float acc = 0.f;
    for (int r = start + wv; r < end; r += 8)
        acc += __half2float(h[(size_t)r * 64 + lane]);
    red[wv][lane] = acc;
    __syncthreads();
    if (wv == 0) {
        float s = red[0][lane];
        #pragma unroll
        for (int w = 1; w < 8; w++) s += red[w][lane];
        float pooled = s / (float)(cnt > 0 ? cnt : 1);
        float p0 = pooled * Wlin[lane * 2 + 0];
        float p1 = pooled * Wlin[lane * 2 + 1];
        #pragma unroll
        for (int off = 32; off > 0; off >>= 1) {
            p0 += __shfl_xor(p0, off);
            p1 += __shfl_xor(p1, off);
        }
        if (lane == 0) {
            p0 += blin[0]; p1 += blin[1];
            float m = fmaxf(p0, p1);
            float e0 = __expf(p0 - m), e1 = __expf(p1 - m);
            float ss = e0 + e1;
            out[g * 2 + 0] = e0 / ss;
            out[g * 2 + 1] = e1 / ss;
        }
    }
}

// ---------------- launch ----------------

extern "C" void kernel_launch(void* const* d_in, const int* in_sizes, int n_in,
                              void* d_out, int out_size, void* d_ws, size_t ws_size,
                              hipStream_t stream) {
    const float* x      = (const float*)d_in[0];
    const int*   ei     = (const int*)d_in[1];
    const float* euclid = (const float*)d_in[2];
    const int*   batch  = (const int*)d_in[3];
    auto P = [&](int i) { return (const float*)d_in[i]; };

    uintptr_t base = (uintptr_t)d_ws;
    auto carve = [&](size_t bytes) {
        uintptr_t r = base;
        base += (bytes + 255) & ~(size_t)255;
        return (void*)r;
    };
    __half* xlh    = (__half*)carve((size_t)NN * 64 * 2);
    __half* xrh    = (__half*)carve((size_t)NN * 64 * 2);
    __half* h1     = (__half*)carve((size_t)NN * 64 * 2);
    __half* h2b    = (__half*)carve((size_t)NN * 64 * 2);
    int*   offs    = (int*)carve((size_t)NN * 4);
    int*   offsE   = (int*)carve((size_t)NN * 4);
    int*   bcur    = (int*)carve((size_t)NB * 16 * 4);
    uint2* bdata   = (uint2*)carve((size_t)NB * BSTRIDE * 8);
    uint32_t* csr  = (uint32_t*)carve((size_t)NB * BSTRIDE * 4);

    int nA = (NE + ACH - 1) / ACH;            // 196 bucketA blocks
    int nGemmBlocks = (NN + 63) / 64;         // 782 gemm blocks
    int nPairWaves = (NN + 1) / 2;            // 25000 waves (2 nodes each)
    int nEdgeBlocks = (nPairWaves * 64 + 255) / 256;  // 6250 blocks

    k_init<<<1, 512, 0, stream>>>(bcur);
    // fused: bucketA || gemm layer 1 (independent work)
    k_phase3<<<nA + nGemmBlocks, 256, 0, stream>>>(
        ei, euclid, bcur, bdata, NE, nA,
        x, P(4), P(5), P(6), P(7), xlh, xrh, NN);
    k_bucketB<<<NB, 256, 0, stream>>>(bcur, bdata, csr, offs, offsE, NN);

    k_edge<<<nEdgeBlocks, 256, 0, stream>>>(xlh, xrh, offs, offsE, csr, P(8), P(9), P(10), h1, NN);
    // layer 2: h1 fp16
    k_gemm4<64, __half><<<nGemmBlocks, 256, 0, stream>>>(h1, P(11), P(12), P(13), P(14), xlh, xrh, NN);
    k_edge<<<nEdgeBlocks, 256, 0, stream>>>(xlh, xrh, offs, offsE, csr, P(15), P(16), P(17), h2b, NN);
    // layer 3: h2 fp16
    k_gemm4<64, __half><<<nGemmBlocks, 256, 0, stream>>>(h2b, P(18), P(19), P(20), P(21), xlh, xrh, NN);
    k_edge<<<nEdgeBlocks, 256, 0, stream>>>(xlh, xrh, offs, offsE, csr, P(22), P(23), P(24), h1, NN);

    k_pool<<<NG, 512, 0, stream>>>(h1, batch, P(25), P(26), (float*)d_out, NN);
}

// Round 16
// 189.920 us; speedup vs baseline: 1.0852x; 1.0508x over previous
//
#include <hip/hip_runtime.h>
#include <hip/hip_bf16.h>
#include <hip/hip_fp16.h>
#include <cstdint>

#define NN 50000
#define NE 800000
#define NG 64
#define NPB 128                      // nodes per bucket
#define NB ((NN + NPB - 1) / NPB)    // 391 buckets
#define BSTRIDE 4096                 // fixed entries per bucket (mean 2046, 22 sigma)
#define BCAP BSTRIDE
#define ACH 4096                     // edges per bucketA block
#define AEPT 16                      // edges per thread (ACH/256)
#define NKEY (NPB * 8)               // counting-sort keys
#define LOG2E 1.44269504f

typedef _Float16 h2 __attribute__((ext_vector_type(2)));

#if defined(__has_builtin)
#if __has_builtin(__builtin_amdgcn_fdot2)
#define HAS_FDOT2 1
#endif
#endif

__device__ __forceinline__ float dot2f(h2 a, h2 b, float c) {
#ifdef HAS_FDOT2
    return __builtin_amdgcn_fdot2(a, b, c, false);
#else
    return c + (float)a[0] * (float)b[0] + (float)a[1] * (float)b[1];
#endif
}

__device__ __forceinline__ h2 bch2(uint32_t u) { return __builtin_bit_cast(h2, u); }

// sum over 8-lane group: quad_perm xor1, xor2, then row_half_mirror (0x141)
__device__ __forceinline__ float row8_sum(float v) {
    int x;
    x = __builtin_amdgcn_update_dpp(0, __builtin_bit_cast(int, v), 0xB1, 0xF, 0xF, true);
    v += __builtin_bit_cast(float, x);
    x = __builtin_amdgcn_update_dpp(0, __builtin_bit_cast(int, v), 0x4E, 0xF, 0xF, true);
    v += __builtin_bit_cast(float, x);
    x = __builtin_amdgcn_update_dpp(0, __builtin_bit_cast(int, v), 0x141, 0xF, 0xF, true);
    v += __builtin_bit_cast(float, x);
    return v;
}

// add value from lane i+8 within the 16-lane row (row_ror:8)
__device__ __forceinline__ float xor8_add(float v) {
    int x = __builtin_amdgcn_update_dpp(0, __builtin_bit_cast(int, v), 0x128, 0xF, 0xF, true);
    return v + __builtin_bit_cast(float, x);
}

// ---------------- init: zero cursors + pre-pack layer constants -------------
// packed layout per layer (128 uints = 512B):
//   [0..31]  We as __half2 bits
//   [32..63] att*LOG2E as __half2 bits
//   [64..127] cb as fp32 bits

__global__ __launch_bounds__(512) void k_init(
    int* __restrict__ bcur, uint32_t* __restrict__ packed,
    const float* __restrict__ We1, const float* __restrict__ att1, const float* __restrict__ cb1,
    const float* __restrict__ We2, const float* __restrict__ att2, const float* __restrict__ cb2,
    const float* __restrict__ We3, const float* __restrict__ att3, const float* __restrict__ cb3) {
    int t = threadIdx.x;
    for (int i = t; i < NB * 16; i += 512) bcur[i] = 0;
    const float* Ws[3] = {We1, We2, We3};
    const float* As[3] = {att1, att2, att3};
    const float* Cs[3] = {cb1, cb2, cb3};
    #pragma unroll
    for (int l = 0; l < 3; l++) {
        uint32_t* pk = packed + l * 128;
        for (int i = t; i < 32; i += 512) {
            __half2 w = __floats2half2_rn(Ws[l][2 * i], Ws[l][2 * i + 1]);
            __half2 a = __floats2half2_rn(As[l][2 * i] * LOG2E, As[l][2 * i + 1] * LOG2E);
            pk[i] = *reinterpret_cast<uint32_t*>(&w);
            pk[32 + i] = *reinterpret_cast<uint32_t*>(&a);
        }
        for (int i = t; i < 64; i += 512) {
            float c = Cs[l][i];
            pk[64 + i] = *reinterpret_cast<uint32_t*>(&c);
        }
    }
}

// ---------------- bucketA body (block-aggregated scatter, fixed-stride) -----

__device__ __forceinline__ void bucketA_body(
    int bid, const int* __restrict__ ei, const float* __restrict__ euclid,
    int* __restrict__ bcur, uint2* __restrict__ bdata, int E) {
    __shared__ int cnt[NB];
    __shared__ int gb[NB];
    int t = threadIdx.x;
    int base = bid * ACH;
    for (int i = t; i < NB; i += 256) cnt[i] = 0;
    __syncthreads();
    uint2 ent[AEPT];
    int bk[AEPT];
    #pragma unroll
    for (int i = 0; i < AEPT; i++) {
        int e = base + i * 256 + t;
        if (e < E) {
            int s = ei[e];
            int d = ei[NE + e];
            unsigned short wh = __half_as_ushort(__float2half(euclid[e]));
            ent[i] = make_uint2(((uint32_t)wh << 16) | (uint32_t)s, (uint32_t)d);
            bk[i] = d >> 7;
            atomicAdd(&cnt[bk[i]], 1);
        } else {
            bk[i] = -1;
        }
    }
    __syncthreads();
    for (int b = t; b < NB; b += 256) {
        int c = cnt[b];
        int old = c ? atomicAdd(&bcur[b * 16], c) : 0;
        gb[b] = b * BSTRIDE + min(old, BSTRIDE);
        cnt[b] = 0;
    }
    __syncthreads();
    #pragma unroll
    for (int i = 0; i < AEPT; i++) {
        if (bk[i] >= 0) {
            int r = atomicAdd(&cnt[bk[i]], 1);
            int pos = gb[bk[i]] + r;
            if (pos < (bk[i] + 1) * BSTRIDE) bdata[pos] = ent[i];
        }
    }
}

// ---------------- GEMM body (fp16 dot2 dual GEMM) ---------------------------

template <int DIN, typename XT>
__device__ __forceinline__ void gemm_body(
    int gb, const XT* __restrict__ X,
    const float* __restrict__ Wl, const float* __restrict__ bl,
    const float* __restrict__ Wr, const float* __restrict__ br,
    __half* __restrict__ xlh, __half* __restrict__ xrh, int n) {
    constexpr int BK = 16, BM = 64, XS = BM + 4, KP = BK / 2;
    constexpr int NKT = DIN / BK;
    __shared__ h2 sX[2][KP][XS];
    __shared__ h2 sW[2][KP][128];
    int t = threadIdx.x;
    int rb = gb * BM;

    int xrow = t >> 2, xk4 = (t & 3) << 2;
    int wkp = t >> 5, wcol = (t & 31) << 2;
    int rg = min(rb + xrow, n - 1);
    const XT* xp = X + (size_t)rg * DIN + xk4;
    const float* wsrc = (wcol < 64) ? (Wl + (2 * wkp) * 64 + wcol)
                                    : (Wr + (2 * wkp) * 64 + wcol - 64);

    h2 gxa, gxb;
    auto loadX2 = [&](const XT* p, h2& a, h2& bq) {
        if constexpr (sizeof(XT) == 4) {
            float4 f = *(const float4*)p;
            a = h2{(_Float16)f.x, (_Float16)f.y};
            bq = h2{(_Float16)f.z, (_Float16)f.w};
        } else {
            uint2 u = *(const uint2*)p;
            a = bch2(u.x);
            bq = bch2(u.y);
        }
    };
    loadX2(xp, gxa, gxb);
    float4 gwa = *(const float4*)wsrc;
    float4 gwb = *(const float4*)(wsrc + 64);

    auto writeTile = [&](int bu) {
        int kp0 = xk4 >> 1;
        sX[bu][kp0][xrow] = gxa;
        sX[bu][kp0 + 1][xrow] = gxb;
        sW[bu][wkp][wcol]     = h2{(_Float16)gwa.x, (_Float16)gwb.x};
        sW[bu][wkp][wcol + 1] = h2{(_Float16)gwa.y, (_Float16)gwb.y};
        sW[bu][wkp][wcol + 2] = h2{(_Float16)gwa.z, (_Float16)gwb.z};
        sW[bu][wkp][wcol + 3] = h2{(_Float16)gwa.w, (_Float16)gwb.w};
    };
    writeTile(0);
    __syncthreads();

    int tx = t & 15, ty = t >> 4;
    int r0 = ty * 4;
    int c0 = tx * 4;
    float acc[4][8];
    #pragma unroll
    for (int i = 0; i < 4; i++)
        #pragma unroll
        for (int j = 0; j < 8; j++) acc[i][j] = 0.f;

    for (int kt = 0; kt < NKT; ++kt) {
        int cur = kt & 1;
        if (kt + 1 < NKT) {
            loadX2(xp + (kt + 1) * BK, gxa, gxb);
            gwa = *(const float4*)(wsrc + (size_t)(kt + 1) * BK * 64);
            gwb = *(const float4*)(wsrc + (size_t)(kt + 1) * BK * 64 + 64);
        }
        #pragma unroll
        for (int kp = 0; kp < KP; kp++) {
            uint4 xa = *(const uint4*)&sX[cur][kp][r0];
            uint4 wa = *(const uint4*)&sW[cur][kp][c0];
            uint4 wb = *(const uint4*)&sW[cur][kp][64 + c0];
            h2 xv[4] = {bch2(xa.x), bch2(xa.y), bch2(xa.z), bch2(xa.w)};
            h2 wv[8] = {bch2(wa.x), bch2(wa.y), bch2(wa.z), bch2(wa.w),
                        bch2(wb.x), bch2(wb.y), bch2(wb.z), bch2(wb.w)};
            #pragma unroll
            for (int ri = 0; ri < 4; ri++)
                #pragma unroll
                for (int cj = 0; cj < 8; cj++)
                    acc[ri][cj] = dot2f(xv[ri], wv[cj], acc[ri][cj]);
        }
        if (kt + 1 < NKT) writeTile((kt + 1) & 1);
        __syncthreads();
    }

    float4 bl4 = *(const float4*)(bl + c0);
    float4 br4 = *(const float4*)(br + c0);
    #pragma unroll
    for (int ri = 0; ri < 4; ri++) {
        int row = rb + r0 + ri;
        if (row < n) {
            __half2 la = __floats2half2_rn(acc[ri][0] + bl4.x, acc[ri][1] + bl4.y);
            __half2 lb = __floats2half2_rn(acc[ri][2] + bl4.z, acc[ri][3] + bl4.w);
            uint2 ul;
            ul.x = *reinterpret_cast<uint32_t*>(&la);
            ul.y = *reinterpret_cast<uint32_t*>(&lb);
            *(uint2*)(xlh + (size_t)row * 64 + c0) = ul;
            __half2 ra = __floats2half2_rn(acc[ri][4] + br4.x, acc[ri][5] + br4.y);
            __half2 rbq = __floats2half2_rn(acc[ri][6] + br4.z, acc[ri][7] + br4.w);
            uint2 ur;
            ur.x = *reinterpret_cast<uint32_t*>(&ra);
            ur.y = *reinterpret_cast<uint32_t*>(&rbq);
            *(uint2*)(xrh + (size_t)row * 64 + c0) = ur;
        }
    }
}

template <int DIN, typename XT>
__global__ __launch_bounds__(256) void k_gemm4(
    const XT* __restrict__ X,
    const float* __restrict__ Wl, const float* __restrict__ bl,
    const float* __restrict__ Wr, const float* __restrict__ br,
    __half* __restrict__ xlh, __half* __restrict__ xrh, int n) {
    gemm_body<DIN, XT>(blockIdx.x, X, Wl, bl, Wr, br, xlh, xrh, n);
}

// fused phase: bucketA (blocks [0,nA)) || gemm layer 1 (blocks [nA, nA+nG))
__global__ __launch_bounds__(256) void k_phase3(
    const int* __restrict__ ei, const float* __restrict__ euclid,
    int* __restrict__ bcur, uint2* __restrict__ bdata, int E, int nA,
    const float* __restrict__ X,
    const float* __restrict__ Wl, const float* __restrict__ bl,
    const float* __restrict__ Wr, const float* __restrict__ br,
    __half* __restrict__ xlh, __half* __restrict__ xrh, int n) {
    if ((int)blockIdx.x < nA) {
        bucketA_body(blockIdx.x, ei, euclid, bcur, bdata, E);
    } else {
        gemm_body<128, float>(blockIdx.x - nA, X, Wl, bl, Wr, br, xlh, xrh, n);
    }
}

// Phase B: per bucket counting-sort by key=(node_local<<3)|(src>>13);
// writes per-node [start,end) into offs/offsE (bucket segments are strided).
__global__ __launch_bounds__(256) void k_bucketB(
    const int* __restrict__ bcur, const uint2* __restrict__ bdata,
    uint32_t* __restrict__ csr, int* __restrict__ offs,
    int* __restrict__ offsE, int n) {
    __shared__ int cnt[NKEY];
    __shared__ int wsum[4];
    __shared__ int nstart[NPB + 1];
    __shared__ uint2 ent_lds[BCAP];
    __shared__ uint32_t obuf[BCAP];
    int b = blockIdx.x;
    int base_node = b * NPB;
    int nnodes = min(NPB, n - base_node);
    int seg0 = b * BSTRIDE;
    int len = min(bcur[b * 16], BSTRIDE);
    int t = threadIdx.x;
    cnt[t] = 0; cnt[t + 256] = 0; cnt[t + 512] = 0; cnt[t + 768] = 0;
    __syncthreads();
    auto keyof = [&](uint2 e) {
        return ((((int)e.y - base_node) << 3) | (int)((e.x & 0xFFFFu) >> 13));
    };
    for (int i = t; i < len; i += 256) {
        uint2 e = bdata[seg0 + i];
        ent_lds[i] = e;
        atomicAdd(&cnt[keyof(e)], 1);
    }
    __syncthreads();
    int c0 = cnt[4 * t], c1 = cnt[4 * t + 1], c2 = cnt[4 * t + 2], c3 = cnt[4 * t + 3];
    int v = c0 + c1 + c2 + c3;
    int lane = t & 63, wv = t >> 6;
    int s = v;
    #pragma unroll
    for (int off = 1; off < 64; off <<= 1) {
        int u = __shfl_up(s, off);
        if (lane >= off) s += u;
    }
    if (lane == 63) wsum[wv] = s;
    __syncthreads();
    int add = 0;
    for (int w = 0; w < wv; w++) add += wsum[w];
    int e0 = s + add - v;
    int e1 = e0 + c0, e2 = e1 + c1, e3 = e2 + c2;
    __syncthreads();
    cnt[4 * t] = e0; cnt[4 * t + 1] = e1; cnt[4 * t + 2] = e2; cnt[4 * t + 3] = e3;
    if ((t & 1) == 0 && (t >> 1) < NPB) nstart[t >> 1] = e0;
    if (t == 0) nstart[nnodes] = len;
    __syncthreads();
    if (t < nnodes) {
        offs[base_node + t]  = seg0 + nstart[t];
        offsE[base_node + t] = seg0 + ((t + 1 < nnodes) ? nstart[t + 1] : len);
    }
    for (int i = t; i < len; i += 256) {
        uint2 e = ent_lds[i];
        int pos = atomicAdd(&cnt[keyof(e)], 1);
        obuf[pos] = e.x;
    }
    __syncthreads();
    for (int i = t; i < len; i += 256) csr[seg0 + i] = obuf[i];
}

// ---------------- edge kernel: ONE node per wave (R13 mapping), 8x8 ---------
// Packed layer constants: 2 uint4 + 2 float4 loads, no converts.

__global__ __launch_bounds__(256) void k_edge(
    const __half* __restrict__ xlh, const __half* __restrict__ xrh,
    const int* __restrict__ offs, const int* __restrict__ offsE,
    const uint32_t* __restrict__ csr, const uint32_t* __restrict__ pk,
    __half* __restrict__ hout, int n) {
    int gtid = blockIdx.x * blockDim.x + threadIdx.x;
    int d = gtid >> 6;
    if (d >= n) return;
    int lane = threadIdx.x & 63;
    int fg = lane & 7;
    int eg = lane >> 3;

    uint4 Weu = *(const uint4*)(pk + fg * 4);
    uint4 atu = *(const uint4*)(pk + 32 + fg * 4);
    const float* pkf = (const float*)pk;
    float4 cba = *(const float4*)(pkf + 64 + fg * 8);
    float4 cbb = *(const float4*)(pkf + 64 + fg * 8 + 4);
    h2 We0 = bch2(Weu.x), We1 = bch2(Weu.y), We2 = bch2(Weu.z), We3 = bch2(Weu.w);
    h2 at0 = bch2(atu.x), at1 = bch2(atu.y), at2 = bch2(atu.z), at3 = bch2(atu.w);
    const h2 k02 = {(_Float16)0.2f, (_Float16)0.2f};

    int s0 = offs[d], s1 = offsE[d];
    int deg = s1 - s0;

    auto storeOut = [&](float o0, float o1, float o2, float o3,
                        float o4, float o5, float o6, float o7) {
        __half2 a = __floats2half2_rn(o0, o1);
        __half2 b = __floats2half2_rn(o2, o3);
        __half2 c = __floats2half2_rn(o4, o5);
        __half2 e = __floats2half2_rn(o6, o7);
        uint4 uo;
        uo.x = *reinterpret_cast<uint32_t*>(&a);
        uo.y = *reinterpret_cast<uint32_t*>(&b);
        uo.z = *reinterpret_cast<uint32_t*>(&c);
        uo.w = *reinterpret_cast<uint32_t*>(&e);
        *(uint4*)(hout + (size_t)d * 64 + fg * 8) = uo;
    };

    if (deg <= 0) {
        if (eg == 0) {
            storeOut(fmaxf(cba.x, 0.f), fmaxf(cba.y, 0.f), fmaxf(cba.z, 0.f),
                     fmaxf(cba.w, 0.f), fmaxf(cbb.x, 0.f), fmaxf(cbb.y, 0.f),
                     fmaxf(cbb.z, 0.f), fmaxf(cbb.w, 0.f));
        }
        return;
    }

    uint4 xru = *(const uint4*)(xrh + (size_t)d * 64 + fg * 8);
    h2 xr0 = bch2(xru.x), xr1 = bch2(xru.y), xr2 = bch2(xru.z), xr3 = bch2(xru.w);
    const char* xbase = (const char*)xlh;
    uint32_t foff = (uint32_t)fg << 4;

    float a0 = 0.f, a1 = 0.f, a2 = 0.f, a3 = 0.f;
    float a4 = 0.f, a5 = 0.f, a6 = 0.f, a7 = 0.f, sum = 0.f;

    int idx0 = min(eg, deg - 1);
    uint32_t ent = csr[s0 + idx0];
    uint4 raw = *(const uint4*)(xbase + ((ent & 0xFFFFu) << 7) + foff);

    for (int base = 0; base < deg; base += 8) {
        bool valid = (base + eg) < deg;
        uint32_t ent_n = ent;
        uint4 raw_n = raw;
        if (base + 8 < deg) {
            int idx2 = min(base + 8 + eg, deg - 1);
            ent_n = csr[s0 + idx2];
            raw_n = *(const uint4*)(xbase + ((ent_n & 0xFFFFu) << 7) + foff);
        }
        h2 xl0 = bch2(raw.x), xl1 = bch2(raw.y), xl2 = bch2(raw.z), xl3 = bch2(raw.w);
        _Float16 wh = __builtin_bit_cast(_Float16, (unsigned short)(ent >> 16));
        h2 w2 = {wh, wh};
        h2 m0 = xl0 + (w2 * We0 + xr0);
        h2 m1 = xl1 + (w2 * We1 + xr1);
        h2 m2 = xl2 + (w2 * We2 + xr2);
        h2 m3 = xl3 + (w2 * We3 + xr3);
        h2 l0 = __builtin_elementwise_max(m0, m0 * k02);
        h2 l1 = __builtin_elementwise_max(m1, m1 * k02);
        h2 l2 = __builtin_elementwise_max(m2, m2 * k02);
        h2 l3 = __builtin_elementwise_max(m3, m3 * k02);
        float p = dot2f(l3, at3, dot2f(l2, at2, dot2f(l1, at1, dot2f(l0, at0, 0.f))));
        p = row8_sum(p);
        float wp = valid ? exp2f(p) : 0.f;
        a0 = fmaf(wp, (float)xl0[0], a0);
        a1 = fmaf(wp, (float)xl0[1], a1);
        a2 = fmaf(wp, (float)xl1[0], a2);
        a3 = fmaf(wp, (float)xl1[1], a3);
        a4 = fmaf(wp, (float)xl2[0], a4);
        a5 = fmaf(wp, (float)xl2[1], a5);
        a6 = fmaf(wp, (float)xl3[0], a6);
        a7 = fmaf(wp, (float)xl3[1], a7);
        sum += wp;
        ent = ent_n;
        raw = raw_n;
    }

    sum = xor8_add(sum);
    a0 = xor8_add(a0); a1 = xor8_add(a1); a2 = xor8_add(a2); a3 = xor8_add(a3);
    a4 = xor8_add(a4); a5 = xor8_add(a5); a6 = xor8_add(a6); a7 = xor8_add(a7);
    #pragma unroll
    for (int off = 16; off <= 32; off <<= 1) {
        sum += __shfl_xor(sum, off);
        a0 += __shfl_xor(a0, off); a1 += __shfl_xor(a1, off);
        a2 += __shfl_xor(a2, off); a3 += __shfl_xor(a3, off);
        a4 += __shfl_xor(a4, off); a5 += __shfl_xor(a5, off);
        a6 += __shfl_xor(a6, off); a7 += __shfl_xor(a7, off);
    }

    if (eg == 0) {
        float inv = 1.0f / sum;
        storeOut(fmaxf(a0 * inv + cba.x, 0.f), fmaxf(a1 * inv + cba.y, 0.f),
                 fmaxf(a2 * inv + cba.z, 0.f), fmaxf(a3 * inv + cba.w, 0.f),
                 fmaxf(a4 * inv + cbb.x, 0.f), fmaxf(a5 * inv + cbb.y, 0.f),
                 fmaxf(a6 * inv + cbb.z, 0.f), fmaxf(a7 * inv + cbb.w, 0.f));
    }
}

// ---------------- fused pooling + head: one block per graph -----------------

__global__ __launch_bounds__(512) void k_pool(
    const __half* __restrict__ h, const int* __restrict__ batch,
    const float* __restrict__ Wlin, const float* __restrict__ blin,
    float* __restrict__ out, int n) {
    __shared__ float red[8][64];
    int g = blockIdx.x;
    int t = threadIdx.x, lane = t & 63, wv = t >> 6;
    int lo = 0, hi = n;
    while (lo < hi) { int mid = (lo + hi) >> 1; if (batch[mid] < g) lo = mid + 1; else hi = mid; }
    int start = lo;
    lo = start; hi = n;
    while (lo < hi) { int mid = (lo + hi) >> 1; if (batch[mid] < g + 1) lo = mid + 1; else hi = mid; }
    int end = lo, cnt = end - start;
    float acc = 0.f;
    for (int r = start + wv; r < end; r += 8)
        acc += __half2float(h[(size_t)r * 64 + lane]);
    red[wv][lane] = acc;
    __syncthreads();
    if (wv == 0) {
        float s = red[0][lane];
        #pragma unroll
        for (int w = 1; w < 8; w++) s += red[w][lane];
        float pooled = s / (float)(cnt > 0 ? cnt : 1);
        float p0 = pooled * Wlin[lane * 2 + 0];
        float p1 = pooled * Wlin[lane * 2 + 1];
        #pragma unroll
        for (int off = 32; off > 0; off >>= 1) {
            p0 += __shfl_xor(p0, off);
            p1 += __shfl_xor(p1, off);
        }
        if (lane == 0) {
            p0 += blin[0]; p1 += blin[1];
            float m = fmaxf(p0, p1);
            float e0 = __expf(p0 - m), e1 = __expf(p1 - m);
            float ss = e0 + e1;
            out[g * 2 + 0] = e0 / ss;
            out[g * 2 + 1] = e1 / ss;
        }
    }
}

// ---------------- launch ----------------

extern "C" void kernel_launch(void* const* d_in, const int* in_sizes, int n_in,
                              void* d_out, int out_size, void* d_ws, size_t ws_size,
                              hipStream_t stream) {
    const float* x      = (const float*)d_in[0];
    const int*   ei     = (const int*)d_in[1];
    const float* euclid = (const float*)d_in[2];
    const int*   batch  = (const int*)d_in[3];
    auto P = [&](int i) { return (const float*)d_in[i]; };

    uintptr_t base = (uintptr_t)d_ws;
    auto carve = [&](size_t bytes) {
        uintptr_t r = base;
        base += (bytes + 255) & ~(size_t)255;
        return (void*)r;
    };
    __half* xlh    = (__half*)carve((size_t)NN * 64 * 2);
    __half* xrh    = (__half*)carve((size_t)NN * 64 * 2);
    __half* h1     = (__half*)carve((size_t)NN * 64 * 2);
    __half* h2b    = (__half*)carve((size_t)NN * 64 * 2);
    int*   offs    = (int*)carve((size_t)NN * 4);
    int*   offsE   = (int*)carve((size_t)NN * 4);
    int*   bcur    = (int*)carve((size_t)NB * 16 * 4);
    uint32_t* packed = (uint32_t*)carve((size_t)3 * 128 * 4);
    uint2* bdata   = (uint2*)carve((size_t)NB * BSTRIDE * 8);
    uint32_t* csr  = (uint32_t*)carve((size_t)NB * BSTRIDE * 4);

    int nA = (NE + ACH - 1) / ACH;            // 196 bucketA blocks
    int nGemmBlocks = (NN + 63) / 64;         // 782 gemm blocks
    int nEdgeBlocks = (NN * 64 + 255) / 256;  // 12500 blocks (1 node/wave)

    k_init<<<1, 512, 0, stream>>>(bcur, packed,
                                  P(8), P(9), P(10),
                                  P(15), P(16), P(17),
                                  P(22), P(23), P(24));
    // fused: bucketA || gemm layer 1 (independent work)
    k_phase3<<<nA + nGemmBlocks, 256, 0, stream>>>(
        ei, euclid, bcur, bdata, NE, nA,
        x, P(4), P(5), P(6), P(7), xlh, xrh, NN);
    k_bucketB<<<NB, 256, 0, stream>>>(bcur, bdata, csr, offs, offsE, NN);

    k_edge<<<nEdgeBlocks, 256, 0, stream>>>(xlh, xrh, offs, offsE, csr, packed + 0, h1, NN);
    // layer 2: h1 fp16
    k_gemm4<64, __half><<<nGemmBlocks, 256, 0, stream>>>(h1, P(11), P(12), P(13), P(14), xlh, xrh, NN);
    k_edge<<<nEdgeBlocks, 256, 0, stream>>>(xlh, xrh, offs, offsE, csr, packed + 128, h2b, NN);
    // layer 3: h2 fp16
    k_gemm4<64, __half><<<nGemmBlocks, 256, 0, stream>>>(h2b, P(18), P(19), P(20), P(21), xlh, xrh, NN);
    k_edge<<<nEdgeBlocks, 256, 0, stream>>>(xlh, xrh, offs, offsE, csr, packed + 256, h1, NN);

    k_pool<<<NG, 512, 0, stream>>>(h1, batch, P(25), P(26), (float*)d_out, NN);
}